// Round 1
// baseline (536.051 us; speedup 1.0000x reference)
//
#include <hip/hip_runtime.h>
#include <stdint.h>

#define NB      256                 // batch
#define HH      512
#define WW      512
#define HWSZ    (HH * WW)           // 262144 floats per plane
#define SPLIT   8                   // blocks per batch in pass 1
#define NBLK1   (NB * SPLIT)        // 2048 blocks (G11: mem-bound sweet spot)
#define THREADS 256
#define F4_PER_BLOCK (HWSZ / 4 / SPLIT)       // 8192 float4 per block
#define ITERS        (F4_PER_BLOCK / THREADS) // 32

// Workspace: every slot written every call (robust to harness poison).
// Cross-kernel visibility via stream/graph dispatch boundaries.
struct Ws {
  unsigned long long bestkey[NBLK1];  // per-pass1-block packed (valbits<<32)|~idx
  float              partial[NBLK1];  // per-pass1-block sum of diff^2
  float              corr[NB];        // per-batch window correction
  unsigned           count;           // last-block-done counter (re-armed by pass1)
};

// ---------------- Pass 1: stream, per-block argmax + sum ----------------
__global__ __launch_bounds__(THREADS) void pass1_kernel(
    const float* __restrict__ outp, const float* __restrict__ tgt,
    Ws* __restrict__ ws) {
  const int blk   = blockIdx.x;
  const int chunk = blk & (SPLIT - 1);
  const size_t base4 = (size_t)blk * F4_PER_BLOCK;   // blk = b*SPLIT+chunk, contiguous
  const float4* o4 = (const float4*)outp + base4;
  const float4* t4 = (const float4*)tgt  + base4;

  const int t = threadIdx.x;
  if (blk == 0 && t == 0) ws->count = 0u;  // re-arm fused finalize (poison-proof)

  float    sum     = 0.0f;
  float    bestv   = -1.0f;            // targets >= 0 -> always overwritten
  unsigned bestidx = 0u;

  #pragma unroll 8
  for (int i = 0; i < ITERS; ++i) {    // coalesced; idx increases per thread
    const int p = i * THREADS + t;
    const float4 ov = o4[p];
    const float4 tv = t4[p];
    const float d0 = ov.x - tv.x, d1 = ov.y - tv.y;
    const float d2 = ov.z - tv.z, d3 = ov.w - tv.w;
    sum += d0 * d0 + d1 * d1 + d2 * d2 + d3 * d3;
    const unsigned fi = (unsigned)((chunk * F4_PER_BLOCK + p) * 4); // idx in plane
    // first-max tournament: strict '>' keeps earliest index; 3-deep dep chain
    float v01 = tv.x; unsigned i01 = fi;
    if (tv.y > v01) { v01 = tv.y; i01 = fi + 1u; }
    float v23 = tv.z; unsigned i23 = fi + 2u;
    if (tv.w > v23) { v23 = tv.w; i23 = fi + 3u; }
    if (v23 > v01) { v01 = v23; i01 = i23; }
    if (v01 > bestv) { bestv = v01; bestidx = i01; }
  }

  // pack: high 32 = float bits (nonneg => order-preserving), low 32 = ~idx
  unsigned long long key =
      ((unsigned long long)__float_as_uint(bestv) << 32) | (unsigned long long)(~bestidx);

  const int lane = t & 63, wave = t >> 6;
  #pragma unroll
  for (int off = 32; off > 0; off >>= 1) {
    unsigned long long ok = __shfl_down(key, off, 64);
    if (ok > key) key = ok;
    sum += __shfl_down(sum, off, 64);
  }
  __shared__ unsigned long long skey[THREADS / 64];
  __shared__ float              ssum[THREADS / 64];
  if (lane == 0) { skey[wave] = key; ssum[wave] = sum; }
  __syncthreads();
  if (t == 0) {
    unsigned long long k = skey[0];
    float s = ssum[0];
    #pragma unroll
    for (int i = 1; i < THREADS / 64; ++i) {
      if (skey[i] > k) k = skey[i];
      s += ssum[i];
    }
    ws->bestkey[blk] = k;    // plain stores, distinct slots — no atomics
    ws->partial[blk] = s;
  }
}

// ---- Pass 2 (fused finalize): per-batch key merge + window correction ----
__global__ __launch_bounds__(THREADS) void pass2_kernel(
    const float* __restrict__ outp, const float* __restrict__ tgt,
    Ws* __restrict__ ws, float* __restrict__ out) {
  const int b = blockIdx.x;
  const int t = threadIdx.x;
  __shared__ unsigned long long s_key;
  if (t == 0) {
    unsigned long long k = ws->bestkey[b * SPLIT];
    #pragma unroll
    for (int i = 1; i < SPLIT; ++i) {
      const unsigned long long ki = ws->bestkey[b * SPLIT + i];
      if (ki > k) k = ki;
    }
    s_key = k;
  }
  __syncthreads();
  const unsigned long long k = s_key;
  const float maxv = __uint_as_float((unsigned)(k >> 32));

  float corr = 0.0f;
  if (maxv >= 0.5f) {
    const unsigned idx = ~(unsigned)(k & 0xFFFFFFFFull);
    const int ph = (int)(idx / WW), pw = (int)(idx % WW);   // WW pow2 -> shifts
    const int dh = HH / 16, dw = WW / 16;                   // 32, 32
    const int top  = max(ph - dh, 0), bot   = min(ph + dh, HH);
    const int left = max(pw - dw, 0), right = min(pw + dw, WW);
    const int Lh = bot - top, Lw = right - left;            // each in [32, 64]
    const float nh = (float)max((Lh + 1) / 2 - 1, 1);       // linspace denom
    const float nw = (float)max((Lw + 1) / 2 - 1, 1);
    const float* ob = outp + (size_t)b * HWSZ;
    const float* tb = tgt  + (size_t)b * HWSZ;
    const int c = t & 63;                 // lane -> column: coalesced, no div/mod
    if (c < Lw) {
      const int kc = min(c, Lw - 1 - c);
      const float vw = 1.0f + 9.0f * (float)kc / nw;
      for (int r = (t >> 6); r < Lh; r += THREADS / 64) {
        const int kr = min(r, Lh - 1 - r);
        const float vh = 1.0f + 9.0f * (float)kr / nh;
        const int off = (top + r) * WW + (left + c);
        const float d = ob[off] - tb[off];
        corr += (vh * vw - 1.0f) * d * d;
      }
    }
  }

  const int lane = t & 63, wave = t >> 6;
  #pragma unroll
  for (int off = 32; off > 0; off >>= 1) corr += __shfl_down(corr, off, 64);
  __shared__ float scorr[THREADS / 64];
  if (lane == 0) scorr[wave] = corr;
  __syncthreads();
  if (t == 0) {
    float s = 0.0f;
    #pragma unroll
    for (int i = 0; i < THREADS / 64; ++i) s += scorr[i];
    ws->corr[b] = s;                                        // plain store
  }
  __threadfence();                      // release corr[b] before count bump

  __shared__ unsigned s_prev;
  if (t == 0) s_prev = atomicAdd(&ws->count, 1u);           // device-scope
  __syncthreads();
  if (s_prev == NB - 1) {               // block-uniform: exactly one last block
    __threadfence();                    // acquire all other blocks' corr stores
    double s = 0.0;
    #pragma unroll
    for (int i = 0; i < NBLK1 / THREADS; ++i) s += (double)ws->partial[i * THREADS + t];
    s += (double)ws->corr[t];           // NB == THREADS
    #pragma unroll
    for (int off = 32; off > 0; off >>= 1) s += __shfl_down(s, off, 64);
    __shared__ double sd[THREADS / 64];
    if (lane == 0) sd[wave] = s;
    __syncthreads();
    if (t == 0) {
      double tot = 0.0;
      #pragma unroll
      for (int i = 0; i < THREADS / 64; ++i) tot += sd[i];
      out[0] = (float)(tot / (double)((size_t)NB * HWSZ));
    }
  }
}

extern "C" void kernel_launch(void* const* d_in, const int* in_sizes, int n_in,
                              void* d_out, int out_size, void* d_ws, size_t ws_size,
                              hipStream_t stream) {
  const float* outp = (const float*)d_in[0];   // "output"
  const float* tgt  = (const float*)d_in[1];   // "target"
  Ws* ws = (Ws*)d_ws;

  pass1_kernel<<<NBLK1, THREADS, 0, stream>>>(outp, tgt, ws);
  pass2_kernel<<<NB, THREADS, 0, stream>>>(outp, tgt, ws, (float*)d_out);
}

// Round 2
// 511.227 us; speedup vs baseline: 1.0486x; 1.0486x over previous
//
#include <hip/hip_runtime.h>
#include <stdint.h>

#define NB      256                 // batch
#define HH      512
#define WW      512
#define HWSZ    (HH * WW)           // 262144 floats per plane
#define SPLIT   16                  // blocks per batch in pass 1 (R0-proven)
#define NBLK1   (NB * SPLIT)        // 4096
#define THREADS 256
#define F4_PER_BLOCK (HWSZ / 4 / SPLIT)       // 4096 float4 per block
#define ITERS        (F4_PER_BLOCK / THREADS) // 16

// Workspace: all plain stores, every slot written every call (no init needed).
// Cross-kernel visibility is guaranteed by stream/graph dispatch boundaries.
struct Ws {
  unsigned long long bestkey[NBLK1];  // per-pass1-block packed (valbits<<32)|~idx
  float              partial[NBLK1];  // per-pass1-block sum of diff^2
  float              corr[NB];        // per-batch window correction
};

// ---------------- Pass 1: stream, per-block argmax + sum ----------------
__global__ __launch_bounds__(THREADS) void pass1_kernel(
    const float* __restrict__ outp, const float* __restrict__ tgt,
    Ws* __restrict__ ws) {
  const int blk   = blockIdx.x;
  const int chunk = blk & (SPLIT - 1);
  const size_t base4 = (size_t)blk * F4_PER_BLOCK;   // blk = b*SPLIT+chunk, contiguous
  const float4* o4 = (const float4*)outp + base4;
  const float4* t4 = (const float4*)tgt  + base4;

  const int t = threadIdx.x;
  float sum   = 0.0f;
  float bestv = -1.0f;               // targets >= 0 -> always overwritten at i=0
  int   bestp = t;                   // winning float4 position (p), decoded later

  #pragma unroll
  for (int i = 0; i < ITERS; ++i) {  // coalesced; idx increases per thread
    const int p = i * THREADS + t;
    const float4 ov = o4[p];
    const float4 tv = t4[p];
    const float d0 = ov.x - tv.x, d1 = ov.y - tv.y;
    const float d2 = ov.z - tv.z, d3 = ov.w - tv.w;
    sum += d0 * d0 + d1 * d1 + d2 * d2 + d3 * d3;
    // value-only max tree (v_max3 + v_max); index deferred to post-loop decode.
    const float m4 = fmaxf(fmaxf(tv.x, tv.y), fmaxf(tv.z, tv.w));
    if (m4 > bestv) { bestv = m4; bestp = p; }  // strict '>': earliest p wins
  }

  // Decode exact element: re-read the one winning float4 (1 load/thread, one-time).
  {
    const float4 tv = t4[bestp];
    const unsigned j = (tv.x == bestv) ? 0u : (tv.y == bestv) ? 1u
                     : (tv.z == bestv) ? 2u : 3u;          // first-equal in-vector
    const unsigned bestidx = (unsigned)((chunk * F4_PER_BLOCK + bestp) * 4) + j;
    // pack: high 32 = float bits (nonneg => order-preserving), low 32 = ~idx
    unsigned long long key =
        ((unsigned long long)__float_as_uint(bestv) << 32) |
        (unsigned long long)(~bestidx);

    const int lane = t & 63, wave = t >> 6;
    #pragma unroll
    for (int off = 32; off > 0; off >>= 1) {
      unsigned long long ok = __shfl_down(key, off, 64);
      if (ok > key) key = ok;
      sum += __shfl_down(sum, off, 64);
    }
    __shared__ unsigned long long skey[THREADS / 64];
    __shared__ float              ssum[THREADS / 64];
    if (lane == 0) { skey[wave] = key; ssum[wave] = sum; }
    __syncthreads();
    if (t == 0) {
      unsigned long long k = skey[0];
      float s = ssum[0];
      #pragma unroll
      for (int i = 1; i < THREADS / 64; ++i) {
        if (skey[i] > k) k = skey[i];
        s += ssum[i];
      }
      ws->bestkey[blk] = k;    // plain stores, distinct slots — no atomics
      ws->partial[blk] = s;
    }
  }
}

// -------- Pass 2: per-batch key merge + window correction (L2/L3-hot) --------
__global__ __launch_bounds__(THREADS) void pass2_kernel(
    const float* __restrict__ outp, const float* __restrict__ tgt,
    Ws* __restrict__ ws) {
  const int b = blockIdx.x;
  const int t = threadIdx.x;
  __shared__ unsigned long long s_key;
  if (t == 0) {
    unsigned long long k = ws->bestkey[b * SPLIT];
    #pragma unroll
    for (int i = 1; i < SPLIT; ++i) {
      const unsigned long long ki = ws->bestkey[b * SPLIT + i];
      if (ki > k) k = ki;
    }
    s_key = k;
  }
  __syncthreads();
  const unsigned long long k = s_key;
  const float maxv = __uint_as_float((unsigned)(k >> 32));

  float corr = 0.0f;
  if (maxv >= 0.5f) {
    const unsigned idx = ~(unsigned)(k & 0xFFFFFFFFull);
    const int ph = (int)(idx / WW), pw = (int)(idx % WW);   // WW pow2 -> shifts
    const int dh = HH / 16, dw = WW / 16;                   // 32, 32
    const int top  = max(ph - dh, 0), bot   = min(ph + dh, HH);
    const int left = max(pw - dw, 0), right = min(pw + dw, WW);
    const int Lh = bot - top, Lw = right - left;            // each in [32, 64]
    const float nh = (float)max((Lh + 1) / 2 - 1, 1);       // linspace denom
    const float nw = (float)max((Lw + 1) / 2 - 1, 1);
    const float* ob = outp + (size_t)b * HWSZ;
    const float* tb = tgt  + (size_t)b * HWSZ;
    const int c = t & 63;                 // lane -> column: coalesced, no div/mod
    if (c < Lw) {
      const int kc = min(c, Lw - 1 - c);
      const float vw = 1.0f + 9.0f * (float)kc / nw;
      for (int r = (t >> 6); r < Lh; r += THREADS / 64) {
        const int kr = min(r, Lh - 1 - r);
        const float vh = 1.0f + 9.0f * (float)kr / nh;
        const int off = (top + r) * WW + (left + c);
        const float d = ob[off] - tb[off];
        corr += (vh * vw - 1.0f) * d * d;
      }
    }
  }

  const int lane = t & 63, wave = t >> 6;
  #pragma unroll
  for (int off = 32; off > 0; off >>= 1) corr += __shfl_down(corr, off, 64);
  __shared__ float ssum[THREADS / 64];
  if (lane == 0) ssum[wave] = corr;
  __syncthreads();
  if (t == 0) {
    float s = 0.0f;
    #pragma unroll
    for (int i = 0; i < THREADS / 64; ++i) s += ssum[i];
    ws->corr[b] = s;                                      // plain store
  }
}

// ---------------- Finalize: one block sums everything in fp64 -------------
__global__ __launch_bounds__(THREADS) void finalize_kernel(
    const Ws* __restrict__ ws, float* __restrict__ out) {
  const int t = threadIdx.x;
  double s = 0.0;
  #pragma unroll
  for (int i = 0; i < NBLK1 / THREADS; ++i) s += (double)ws->partial[i * THREADS + t];
  s += (double)ws->corr[t];                               // NB == THREADS

  const int lane = t & 63, wave = t >> 6;
  #pragma unroll
  for (int off = 32; off > 0; off >>= 1) s += __shfl_down(s, off, 64);
  __shared__ double sd[THREADS / 64];
  if (lane == 0) sd[wave] = s;
  __syncthreads();
  if (t == 0) {
    double tot = 0.0;
    #pragma unroll
    for (int i = 0; i < THREADS / 64; ++i) tot += sd[i];
    out[0] = (float)(tot / (double)((size_t)NB * HWSZ));
  }
}

extern "C" void kernel_launch(void* const* d_in, const int* in_sizes, int n_in,
                              void* d_out, int out_size, void* d_ws, size_t ws_size,
                              hipStream_t stream) {
  const float* outp = (const float*)d_in[0];   // "output"
  const float* tgt  = (const float*)d_in[1];   // "target"
  Ws* ws = (Ws*)d_ws;

  pass1_kernel<<<NBLK1, THREADS, 0, stream>>>(outp, tgt, ws);
  pass2_kernel<<<NB, THREADS, 0, stream>>>(outp, tgt, ws);
  finalize_kernel<<<1, THREADS, 0, stream>>>(ws, (float*)d_out);
}